// Round 1
// baseline (5624.922 us; speedup 1.0000x reference)
//
#include <hip/hip_runtime.h>
#include <hip/hip_bf16.h>
#include <math.h>

#define BB 64
#define TT 128
#define T1 127
#define NNODE 2000
#define EE 300
#define HID 256
#define NHEADS 5
#define DD 16
#define G3 768
#define ATT 1280

// ---------------- transpose (elementwise) ----------------
__global__ void k_transpose(const float* __restrict__ src, float* __restrict__ dst, int R, int C) {
    int idx = blockIdx.x * 256 + threadIdx.x;
    if (idx < R * C) {
        int r = idx / C, c = idx % C;
        dst[c * R + r] = src[idx];
    }
}

// ---------------- tiled f32 GEMM with gather modes ----------------
// out[m][g] = sum_c A_row(m)[c] * Bmat[brow0+c][g]  (+bias, tanh optional)
// mode 0: A row base = m*K (program_emb)     mode 1: same, M-guarded (node_emb)
// mode 2: label gather via trace/na          mode 3: A=store rows (m*K)
__global__ __launch_bounds__(256) void k_gemm(
    const float* __restrict__ A, const float* __restrict__ Bmat,
    float* __restrict__ out, const float* __restrict__ bias,
    const int* __restrict__ trace, const int* __restrict__ na,
    int mode, int M, int K, int N, int ntiles, int brow0, int dotanh)
{
    __shared__ float As[64][17];
    __shared__ float Bs[16][65];
    __shared__ int baseLds[64];
    __shared__ int validLds[64];
    int tid = threadIdx.x;
    int bm = blockIdx.x / ntiles, bn = blockIdx.x % ntiles;
    int m0 = bm * 64, n0 = bn * 64;
    if (tid < 64) {
        int m = m0 + tid;
        int valid = (m < M) ? 1 : 0;
        int base = 0;
        if (valid) {
            if (mode == 2) {
                int i = m >> 6, b = m & 63;
                int node = trace[b * TT + i];
                int asg = (node < NNODE) ? na[b * NNODE + node] : 0;
                base = (node * DD + asg) * EE;
            } else {
                base = m * K;
            }
        }
        baseLds[tid] = base;
        validLds[tid] = valid;
    }
    __syncthreads();
    int tr = tid >> 4, tc = tid & 15;
    float acc[4][4];
#pragma unroll
    for (int x = 0; x < 4; x++)
#pragma unroll
        for (int y = 0; y < 4; y++) acc[x][y] = 0.f;
    int iters = (K + 15) >> 4;
    for (int it = 0; it < iters; it++) {
        int kk = it * 16;
#pragma unroll
        for (int l = 0; l < 4; l++) {
            int ii = tid + l * 256;
            int r = ii >> 4, c = ii & 15;
            float v = 0.f;
            if (validLds[r] && (kk + c) < K) v = A[(size_t)baseLds[r] + kk + c];
            As[r][c] = v;
        }
#pragma unroll
        for (int l = 0; l < 4; l++) {
            int ii = tid + l * 256;
            int c = ii >> 6, g = ii & 63;
            float v = 0.f;
            if ((kk + c) < K) v = Bmat[(size_t)(brow0 + kk + c) * N + n0 + g];
            Bs[c][g] = v;
        }
        __syncthreads();
#pragma unroll
        for (int c = 0; c < 16; c++) {
            float a0 = As[tr * 4 + 0][c], a1 = As[tr * 4 + 1][c];
            float a2 = As[tr * 4 + 2][c], a3 = As[tr * 4 + 3][c];
            float b0 = Bs[c][tc * 4 + 0], b1 = Bs[c][tc * 4 + 1];
            float b2 = Bs[c][tc * 4 + 2], b3 = Bs[c][tc * 4 + 3];
            acc[0][0] += a0 * b0; acc[0][1] += a0 * b1; acc[0][2] += a0 * b2; acc[0][3] += a0 * b3;
            acc[1][0] += a1 * b0; acc[1][1] += a1 * b1; acc[1][2] += a1 * b2; acc[1][3] += a1 * b3;
            acc[2][0] += a2 * b0; acc[2][1] += a2 * b1; acc[2][2] += a2 * b2; acc[2][3] += a2 * b3;
            acc[3][0] += a3 * b0; acc[3][1] += a3 * b1; acc[3][2] += a3 * b2; acc[3][3] += a3 * b3;
        }
        __syncthreads();
    }
#pragma unroll
    for (int x = 0; x < 4; x++) {
        int row = m0 + tr * 4 + x;
        if (row < M) {
#pragma unroll
            for (int y = 0; y < 4; y++) {
                float v = acc[x][y];
                int col = n0 + tc * 4 + y;
                if (bias) v += bias[col];
                if (dotanh) v = tanhf(v);
                out[(size_t)row * N + col] = v;
            }
        }
    }
}

// ---------------- sequential GRU recurrence (persistent, custom grid barrier) ----------------
__global__ __launch_bounds__(256) void rec_kernel(
    const float* __restrict__ h0, const float* __restrict__ whh, const float* __restrict__ bhh,
    const float* __restrict__ prog_t, const float* __restrict__ node_t, const float* __restrict__ label_p,
    const int* __restrict__ trace, float* __restrict__ store, unsigned* __restrict__ bar)
{
    const int tid = threadIdx.x;
    const int s = tid & 3;              // K-split (4 × 64 columns)
    const int kl = (tid >> 2) & 3;      // k within tile
    const int bl = tid >> 4;            // batch within tile (0..15)
    const int kt = blockIdx.x & 63;     // 64 k-tiles of 4
    const int bt = blockIdx.x >> 6;     // 4 b-tiles of 16
    const int k = kt * 4 + kl;
    const int b = bt * 16 + bl;
    const float* wr = whh + (size_t)k * HID + s * 64;
    const float* wz = whh + (size_t)(HID + k) * HID + s * 64;
    const float* wn = whh + (size_t)(2 * HID + k) * HID + s * 64;
    const float bhr = bhh[k], bhz = bhh[HID + k], bhn = bhh[2 * HID + k];
    const float pr = prog_t[b * G3 + k], pz = prog_t[b * G3 + HID + k], pn = prog_t[b * G3 + 2 * HID + k];

    for (int i = 0; i < T1; i++) {
        const float* hp = (i == 0) ? (h0 + (size_t)b * HID) : (store + ((size_t)b * T1 + (i - 1)) * HID);
        const float* hps = hp + s * 64;
        float ar = 0.f, az = 0.f, an = 0.f;
#pragma unroll
        for (int c = 0; c < 64; c += 4) {
            float4 h4 = *(const float4*)(hps + c);
            float4 r4 = *(const float4*)(wr + c);
            float4 z4 = *(const float4*)(wz + c);
            float4 n4 = *(const float4*)(wn + c);
            ar += h4.x * r4.x + h4.y * r4.y + h4.z * r4.z + h4.w * r4.w;
            az += h4.x * z4.x + h4.y * z4.y + h4.z * z4.z + h4.w * z4.w;
            an += h4.x * n4.x + h4.y * n4.y + h4.z * n4.z + h4.w * n4.w;
        }
        ar += __shfl_xor(ar, 1); ar += __shfl_xor(ar, 2);
        az += __shfl_xor(az, 1); az += __shfl_xor(az, 2);
        an += __shfl_xor(an, 1); an += __shfl_xor(an, 2);
        if (s == 0) {
            const int node = trace[b * TT + i];
            const float* lp = label_p + ((size_t)i * BB + b) * G3;
            const float* nt = node_t + (size_t)node * G3;
            float gir = lp[k] + nt[k] + pr;
            float giz = lp[HID + k] + nt[HID + k] + pz;
            float gin = lp[2 * HID + k] + nt[2 * HID + k] + pn;
            float r = 1.f / (1.f + expf(-(gir + ar + bhr)));
            float z = 1.f / (1.f + expf(-(giz + az + bhz)));
            float n = tanhf(gin + r * (an + bhn));
            float hold = hp[k];
            store[((size_t)b * T1 + i) * HID + k] = (1.f - z) * n + z * hold;
        }
        // ---- grid barrier (sense via generation counter) ----
        __syncthreads();
        if (tid == 0) {
            __threadfence();
            unsigned g0 = __hip_atomic_load(bar + 1, __ATOMIC_ACQUIRE, __HIP_MEMORY_SCOPE_AGENT);
            unsigned arrived = __hip_atomic_fetch_add(bar, 1u, __ATOMIC_ACQ_REL, __HIP_MEMORY_SCOPE_AGENT);
            if (arrived == 255u) {
                __hip_atomic_store(bar, 0u, __ATOMIC_RELAXED, __HIP_MEMORY_SCOPE_AGENT);
                __hip_atomic_fetch_add(bar + 1, 1u, __ATOMIC_ACQ_REL, __HIP_MEMORY_SCOPE_AGENT);
            } else {
                while (__hip_atomic_load(bar + 1, __ATOMIC_ACQUIRE, __HIP_MEMORY_SCOPE_AGENT) == g0)
                    __builtin_amdgcn_s_sleep(1);
            }
            __threadfence();
        }
        __syncthreads();
    }
}

// ---------------- scores = U @ ws2^T ----------------
__global__ void k_scores(const float* __restrict__ U, const float* __restrict__ ws2, float* __restrict__ sbuf) {
    int flat = blockIdx.x * 256 + threadIdx.x;
    if (flat < BB * T1 * NHEADS) {
        int m = flat / NHEADS, h = flat % NHEADS;
        const float* u = U + (size_t)m * HID;
        const float* w = ws2 + h * HID;
        float acc = 0.f;
        for (int c = 0; c < HID; c += 4) {
            float4 u4 = *(const float4*)(u + c);
            float4 w4 = *(const float4*)(w + c);
            acc += u4.x * w4.x + u4.y * w4.y + u4.z * w4.z + u4.w * w4.w;
        }
        sbuf[flat] = acc;
    }
}

// ---------------- per-(b,h) global max + exp + prefix denominators ----------------
__global__ void k_softmax_scan(const float* __restrict__ sbuf, float* __restrict__ ebuf, float* __restrict__ rD) {
    int tid = threadIdx.x;
    if (tid < BB * NHEADS) {
        int b = tid / NHEADS, h = tid % NHEADS;
        const float* s = sbuf + (size_t)b * T1 * NHEADS + h;
        float m = -1e30f;
        for (int t = 0; t < T1; t++) m = fmaxf(m, s[t * NHEADS]);
        float d = 0.f;
        for (int t = 0; t < T1; t++) {
            float e = expf(s[t * NHEADS] - m);
            ebuf[(b * T1 + t) * NHEADS + h] = e;
            d += e;
            rD[(b * T1 + t) * NHEADS + h] = 1.f / d;
        }
    }
}

// ---------------- alphas output ----------------
__global__ void k_alphas(const float* __restrict__ ebuf, const float* __restrict__ rD, float* __restrict__ alph) {
    int flat = blockIdx.x * 256 + threadIdx.x;
    const int TOT = T1 * BB * T1 * NHEADS;
    if (flat < TOT) {
        int i = flat / (BB * T1 * NHEADS);
        int rem = flat % (BB * T1 * NHEADS);
        int b = rem / (T1 * NHEADS);
        int rem2 = rem % (T1 * NHEADS);
        int t = rem2 / NHEADS, h = rem2 % NHEADS;
        float v = 0.f;
        if (t <= i) v = ebuf[(b * T1 + t) * NHEADS + h] * rD[(b * T1 + i) * NHEADS + h];
        alph[flat] = v;
    }
}

// ---------------- ctx prefix scan ----------------
__global__ void k_ctx(const float* __restrict__ ebuf, const float* __restrict__ rD,
                      const float* __restrict__ store, float* __restrict__ ctx) {
    int b = blockIdx.x / NHEADS, h = blockIdx.x % NHEADS;
    int k = threadIdx.x;
    float acc = 0.f;
    for (int t = 0; t < T1; t++) {
        float e = ebuf[(b * T1 + t) * NHEADS + h];
        float r = rD[(b * T1 + t) * NHEADS + h];
        acc += e * store[((size_t)b * T1 + t) * HID + k];
        ctx[((size_t)t * BB + b) * ATT + h * HID + k] = acc * r;
    }
}

// ---------------- routed prediction heads ----------------
__global__ __launch_bounds__(64) void k_pred(const float* __restrict__ ctx, const float* __restrict__ pw,
                                             const float* __restrict__ pb, const int* __restrict__ trace,
                                             float* __restrict__ outs) {
    __shared__ float cl[ATT];
    __shared__ float ps[4][DD];
    int bid = blockIdx.x;           // i*64 + b
    int i = bid >> 6, b = bid & 63;
    int tid = threadIdx.x;
    for (int idx = tid; idx < ATT; idx += 64) cl[idx] = ctx[(size_t)bid * ATT + idx];
    __syncthreads();
    int node1 = trace[b * TT + i + 1];
    const float* w = pw + (size_t)node1 * ATT * DD;
    int d = tid & 15, sg = tid >> 4;
    float acc = 0.f;
    for (int k = sg * 320; k < sg * 320 + 320; k++) acc += cl[k] * w[k * DD + d];
    ps[sg][d] = acc;
    __syncthreads();
    if (tid < DD) {
        float o = ps[0][tid] + ps[1][tid] + ps[2][tid] + ps[3][tid] + pb[node1 * DD + tid];
        outs[(size_t)bid * DD + tid] = o;
    }
}

extern "C" void kernel_launch(void* const* d_in, const int* in_sizes, int n_in,
                              void* d_out, int out_size, void* d_ws, size_t ws_size,
                              hipStream_t stream) {
    const float* program_emb = (const float*)d_in[0];
    const float* h0       = (const float*)d_in[1];
    const float* node_emb = (const float*)d_in[2];
    const float* label_emb= (const float*)d_in[3];
    const float* w_ih     = (const float*)d_in[4];
    const float* w_hh     = (const float*)d_in[5];
    const float* b_ih     = (const float*)d_in[6];
    const float* b_hh     = (const float*)d_in[7];
    const float* ws1      = (const float*)d_in[8];
    const float* ws2      = (const float*)d_in[9];
    const float* pred_w   = (const float*)d_in[10];
    const float* pred_b   = (const float*)d_in[11];
    const int*   trace    = (const int*)d_in[12];
    const int*   na       = (const int*)d_in[13];

    float* ws = (float*)d_ws;
    float* store   = ws + 0;          // 64*127*256      = 2,080,768
    float* wihT    = ws + 2080768;    // 856*768         =   657,408
    float* ws1T    = ws + 2738176;    // 256*256         =    65,536
    float* prog_t  = ws + 2803712;    // 64*768          =    49,152
    float* node_t  = ws + 2852864;    // 2001*768        = 1,536,768
    float* sbuf    = ws + 4389632;    // 64*127*5        =    40,640
    float* ebuf    = ws + 4430272;    //                 =    40,640
    float* rD      = ws + 4470912;    //                 =    40,640
    unsigned* bar  = (unsigned*)(ws + 4511552);  // 16 floats reserved
    float* label_p = ws + 4511568;    // 127*64*768      = 6,242,304   [dead after rec]
    float* Ubuf    = ws + 10753872;   // 8128*256        = 2,080,768   [dead after k_scores]
    float* ctx     = ws + 4511568;    // 127*64*1280     = 10,403,840  (aliases label_p+Ubuf)

    float* outs = (float*)d_out;
    float* alph = outs + T1 * BB * DD;   // offset 130048

    // P1: static precompute
    k_transpose<<<2568, 256, 0, stream>>>(w_ih, wihT, G3, 856);
    k_transpose<<<256, 256, 0, stream>>>(ws1, ws1T, HID, HID);
    k_gemm<<<12,   256, 0, stream>>>(program_emb, wihT, prog_t, b_ih, nullptr, nullptr, 0, 64,   256, G3, 12, 300, 0);
    k_gemm<<<384,  256, 0, stream>>>(node_emb,    wihT, node_t, nullptr, nullptr, nullptr, 1, 2001, 300, G3, 12, 556, 0);
    k_gemm<<<1524, 256, 0, stream>>>(label_emb,   wihT, label_p, nullptr, trace, na,       2, 8128, 300, G3, 12, 0,   0);

    // P2: sequential recurrence
    hipMemsetAsync(bar, 0, 8, stream);
    rec_kernel<<<256, 256, 0, stream>>>(h0, w_hh, b_hh, prog_t, node_t, label_p, trace, store, bar);

    // P3: parallel attention + prediction
    k_gemm<<<508, 256, 0, stream>>>(store, ws1T, Ubuf, nullptr, nullptr, nullptr, 3, 8128, 256, HID, 4, 0, 1);
    k_scores<<<159, 256, 0, stream>>>(Ubuf, ws2, sbuf);
    k_softmax_scan<<<1, 512, 0, stream>>>(sbuf, ebuf, rD);
    k_alphas<<<20162, 256, 0, stream>>>(ebuf, rD, alph);
    k_ctx<<<320, 256, 0, stream>>>(ebuf, rD, store, ctx);
    k_pred<<<8128, 64, 0, stream>>>(ctx, pred_w, pred_b, trace, outs);
}

// Round 2
// 894.605 us; speedup vs baseline: 6.2876x; 6.2876x over previous
//
#include <hip/hip_runtime.h>
#include <hip/hip_bf16.h>
#include <math.h>

#define BB 64
#define TT 128
#define T1 127
#define NNODE 2000
#define EE 300
#define HID 256
#define NHEADS 5
#define DD 16
#define G3 768
#define ATT 1280

typedef _Float16 h2_t __attribute__((ext_vector_type(2)));

__device__ __forceinline__ float fdot2(h2_t a, h2_t b, float c) {
#if __has_builtin(__builtin_amdgcn_fdot2)
    return __builtin_amdgcn_fdot2(a, b, c, false);
#else
    return c + (float)a[0] * (float)b[0] + (float)a[1] * (float)b[1];
#endif
}

// ---------------- transpose (elementwise) ----------------
__global__ void k_transpose(const float* __restrict__ src, float* __restrict__ dst, int R, int C) {
    int idx = blockIdx.x * 256 + threadIdx.x;
    if (idx < R * C) {
        int r = idx / C, c = idx % C;
        dst[c * R + r] = src[idx];
    }
}

// ---------------- f32 -> f16 convert ----------------
__global__ void k_cvt(const float* __restrict__ src, _Float16* __restrict__ dst, int n) {
    int i = blockIdx.x * 256 + threadIdx.x;
    if (i < n) dst[i] = (_Float16)src[i];
}

// ---------------- tiled f32 GEMM with gather modes ----------------
__global__ __launch_bounds__(256) void k_gemm(
    const float* __restrict__ A, const float* __restrict__ Bmat,
    float* __restrict__ out, const float* __restrict__ bias,
    const int* __restrict__ trace, const int* __restrict__ na,
    int mode, int M, int K, int N, int ntiles, int brow0, int dotanh)
{
    __shared__ float As[64][17];
    __shared__ float Bs[16][65];
    __shared__ int baseLds[64];
    __shared__ int validLds[64];
    int tid = threadIdx.x;
    int bm = blockIdx.x / ntiles, bn = blockIdx.x % ntiles;
    int m0 = bm * 64, n0 = bn * 64;
    if (tid < 64) {
        int m = m0 + tid;
        int valid = (m < M) ? 1 : 0;
        int base = 0;
        if (valid) {
            if (mode == 2) {
                int i = m >> 6, b = m & 63;
                int node = trace[b * TT + i];
                int asg = (node < NNODE) ? na[b * NNODE + node] : 0;
                base = (node * DD + asg) * EE;
            } else {
                base = m * K;
            }
        }
        baseLds[tid] = base;
        validLds[tid] = valid;
    }
    __syncthreads();
    int tr = tid >> 4, tc = tid & 15;
    float acc[4][4];
#pragma unroll
    for (int x = 0; x < 4; x++)
#pragma unroll
        for (int y = 0; y < 4; y++) acc[x][y] = 0.f;
    int iters = (K + 15) >> 4;
    for (int it = 0; it < iters; it++) {
        int kk = it * 16;
#pragma unroll
        for (int l = 0; l < 4; l++) {
            int ii = tid + l * 256;
            int r = ii >> 4, c = ii & 15;
            float v = 0.f;
            if (validLds[r] && (kk + c) < K) v = A[(size_t)baseLds[r] + kk + c];
            As[r][c] = v;
        }
#pragma unroll
        for (int l = 0; l < 4; l++) {
            int ii = tid + l * 256;
            int c = ii >> 6, g = ii & 63;
            float v = 0.f;
            if ((kk + c) < K) v = Bmat[(size_t)(brow0 + kk + c) * N + n0 + g];
            Bs[c][g] = v;
        }
        __syncthreads();
#pragma unroll
        for (int c = 0; c < 16; c++) {
            float a0 = As[tr * 4 + 0][c], a1 = As[tr * 4 + 1][c];
            float a2 = As[tr * 4 + 2][c], a3 = As[tr * 4 + 3][c];
            float b0 = Bs[c][tc * 4 + 0], b1 = Bs[c][tc * 4 + 1];
            float b2 = Bs[c][tc * 4 + 2], b3 = Bs[c][tc * 4 + 3];
            acc[0][0] += a0 * b0; acc[0][1] += a0 * b1; acc[0][2] += a0 * b2; acc[0][3] += a0 * b3;
            acc[1][0] += a1 * b0; acc[1][1] += a1 * b1; acc[1][2] += a1 * b2; acc[1][3] += a1 * b3;
            acc[2][0] += a2 * b0; acc[2][1] += a2 * b1; acc[2][2] += a2 * b2; acc[2][3] += a2 * b3;
            acc[3][0] += a3 * b0; acc[3][1] += a3 * b1; acc[3][2] += a3 * b2; acc[3][3] += a3 * b3;
        }
        __syncthreads();
    }
#pragma unroll
    for (int x = 0; x < 4; x++) {
        int row = m0 + tr * 4 + x;
        if (row < M) {
#pragma unroll
            for (int y = 0; y < 4; y++) {
                float v = acc[x][y];
                int col = n0 + tc * 4 + y;
                if (bias) v += bias[col];
                if (dotanh) v = tanhf(v);
                out[(size_t)row * N + col] = v;
            }
        }
    }
}

// ---------------- GRU recurrence: per-batch independent, no grid sync ----------------
// 32 blocks x 512 threads. Block handles batches {2*blk, 2*blk+1}.
// tid = k*2 + s : k = output row (0..255), s = K-half (0/1). Pair-reduce via shfl_xor(1).
__global__ __launch_bounds__(512) void rec2_kernel(
    const float* __restrict__ h0, const _Float16* __restrict__ whh16, const float* __restrict__ bhh,
    const float* __restrict__ prog_t, const float* __restrict__ node_t, const float* __restrict__ label_p,
    const int* __restrict__ trace, float* __restrict__ store)
{
    __shared__ float hs32[2][HID];
    __shared__ _Float16 hs16[2 * HID];

    const int tid = threadIdx.x;
    const int s = tid & 1;
    const int k = tid >> 1;
    const int b0 = blockIdx.x * 2;

    // init h
    {
        int bb = tid >> 8, kk = tid & 255;
        float v = h0[(size_t)(b0 + bb) * HID + kk];
        hs32[bb][kk] = v;
        hs16[bb * HID + kk] = (_Float16)v;
    }
    __syncthreads();

    union H8 { uint4 u; h2_t h[4]; };
    const H8* wr = (const H8*)(whh16 + (size_t)k * HID + s * 128);
    const H8* wz = (const H8*)(whh16 + (size_t)(HID + k) * HID + s * 128);
    const H8* wn = (const H8*)(whh16 + (size_t)(2 * HID + k) * HID + s * 128);
    const float bhr = bhh[k], bhz = bhh[HID + k], bhn = bhh[2 * HID + k];
    const float pr0 = prog_t[(b0 + 0) * G3 + k], pz0 = prog_t[(b0 + 0) * G3 + HID + k], pn0 = prog_t[(b0 + 0) * G3 + 2 * HID + k];
    const float pr1 = prog_t[(b0 + 1) * G3 + k], pz1 = prog_t[(b0 + 1) * G3 + HID + k], pn1 = prog_t[(b0 + 1) * G3 + 2 * HID + k];

    for (int i = 0; i < T1; i++) {
        float ar0 = 0.f, az0 = 0.f, an0 = 0.f, ar1 = 0.f, az1 = 0.f, an1 = 0.f;
        const H8* h8a = (const H8*)(hs16 + 0 * HID + s * 128);
        const H8* h8b = (const H8*)(hs16 + 1 * HID + s * 128);
#pragma unroll
        for (int cc = 0; cc < 16; cc++) {
            H8 wR = wr[cc], wZ = wz[cc], wN = wn[cc];
            H8 hA = h8a[cc], hB = h8b[cc];
#pragma unroll
            for (int j = 0; j < 4; j++) {
                ar0 = fdot2(wR.h[j], hA.h[j], ar0);
                az0 = fdot2(wZ.h[j], hA.h[j], az0);
                an0 = fdot2(wN.h[j], hA.h[j], an0);
                ar1 = fdot2(wR.h[j], hB.h[j], ar1);
                az1 = fdot2(wZ.h[j], hB.h[j], az1);
                an1 = fdot2(wN.h[j], hB.h[j], an1);
            }
        }
        // combine K-halves (lanes 2k / 2k+1)
        ar0 += __shfl_xor(ar0, 1); az0 += __shfl_xor(az0, 1); an0 += __shfl_xor(an0, 1);
        ar1 += __shfl_xor(ar1, 1); az1 += __shfl_xor(az1, 1); an1 += __shfl_xor(an1, 1);

        __syncthreads();   // all hs16 reads of this step complete

        if (s == 0) {
#pragma unroll
            for (int bb = 0; bb < 2; bb++) {
                const int b = b0 + bb;
                const int node = trace[b * TT + i];
                const float* lp = label_p + ((size_t)i * BB + b) * G3;
                const float* nt = node_t + (size_t)node * G3;
                float pr = bb ? pr1 : pr0, pz = bb ? pz1 : pz0, pn = bb ? pn1 : pn0;
                float ar = bb ? ar1 : ar0, az = bb ? az1 : az0, an = bb ? an1 : an0;
                float gir = lp[k] + nt[k] + pr;
                float giz = lp[HID + k] + nt[HID + k] + pz;
                float gin = lp[2 * HID + k] + nt[2 * HID + k] + pn;
                float r = 1.f / (1.f + expf(-(gir + ar + bhr)));
                float z = 1.f / (1.f + expf(-(giz + az + bhz)));
                float n = tanhf(gin + r * (an + bhn));
                float hold = hs32[bb][k];
                float hnew = (1.f - z) * n + z * hold;
                hs32[bb][k] = hnew;
                hs16[bb * HID + k] = (_Float16)hnew;
                store[((size_t)b * T1 + i) * HID + k] = hnew;
            }
        }
        __syncthreads();   // writes visible before next step's reads
    }
}

// ---------------- scores = U @ ws2^T ----------------
__global__ void k_scores(const float* __restrict__ U, const float* __restrict__ ws2, float* __restrict__ sbuf) {
    int flat = blockIdx.x * 256 + threadIdx.x;
    if (flat < BB * T1 * NHEADS) {
        int m = flat / NHEADS, h = flat % NHEADS;
        const float* u = U + (size_t)m * HID;
        const float* w = ws2 + h * HID;
        float acc = 0.f;
        for (int c = 0; c < HID; c += 4) {
            float4 u4 = *(const float4*)(u + c);
            float4 w4 = *(const float4*)(w + c);
            acc += u4.x * w4.x + u4.y * w4.y + u4.z * w4.z + u4.w * w4.w;
        }
        sbuf[flat] = acc;
    }
}

// ---------------- per-(b,h) global max + exp + prefix denominators ----------------
__global__ void k_softmax_scan(const float* __restrict__ sbuf, float* __restrict__ ebuf, float* __restrict__ rD) {
    int tid = threadIdx.x;
    if (tid < BB * NHEADS) {
        int b = tid / NHEADS, h = tid % NHEADS;
        const float* s = sbuf + (size_t)b * T1 * NHEADS + h;
        float m = -1e30f;
        for (int t = 0; t < T1; t++) m = fmaxf(m, s[t * NHEADS]);
        float d = 0.f;
        for (int t = 0; t < T1; t++) {
            float e = expf(s[t * NHEADS] - m);
            ebuf[(b * T1 + t) * NHEADS + h] = e;
            d += e;
            rD[(b * T1 + t) * NHEADS + h] = 1.f / d;
        }
    }
}

// ---------------- alphas output ----------------
__global__ void k_alphas(const float* __restrict__ ebuf, const float* __restrict__ rD, float* __restrict__ alph) {
    int flat = blockIdx.x * 256 + threadIdx.x;
    const int TOT = T1 * BB * T1 * NHEADS;
    if (flat < TOT) {
        int i = flat / (BB * T1 * NHEADS);
        int rem = flat % (BB * T1 * NHEADS);
        int b = rem / (T1 * NHEADS);
        int rem2 = rem % (T1 * NHEADS);
        int t = rem2 / NHEADS, h = rem2 % NHEADS;
        float v = 0.f;
        if (t <= i) v = ebuf[(b * T1 + t) * NHEADS + h] * rD[(b * T1 + i) * NHEADS + h];
        alph[flat] = v;
    }
}

// ---------------- ctx prefix scan ----------------
__global__ void k_ctx(const float* __restrict__ ebuf, const float* __restrict__ rD,
                      const float* __restrict__ store, float* __restrict__ ctx) {
    int b = blockIdx.x / NHEADS, h = blockIdx.x % NHEADS;
    int k = threadIdx.x;
    float acc = 0.f;
    for (int t = 0; t < T1; t++) {
        float e = ebuf[(b * T1 + t) * NHEADS + h];
        float r = rD[(b * T1 + t) * NHEADS + h];
        acc += e * store[((size_t)b * T1 + t) * HID + k];
        ctx[((size_t)t * BB + b) * ATT + h * HID + k] = acc * r;
    }
}

// ---------------- routed prediction heads ----------------
__global__ __launch_bounds__(64) void k_pred(const float* __restrict__ ctx, const float* __restrict__ pw,
                                             const float* __restrict__ pb, const int* __restrict__ trace,
                                             float* __restrict__ outs) {
    __shared__ float cl[ATT];
    __shared__ float ps[4][DD];
    int bid = blockIdx.x;           // i*64 + b
    int i = bid >> 6, b = bid & 63;
    int tid = threadIdx.x;
    for (int idx = tid; idx < ATT; idx += 64) cl[idx] = ctx[(size_t)bid * ATT + idx];
    __syncthreads();
    int node1 = trace[b * TT + i + 1];
    const float* w = pw + (size_t)node1 * ATT * DD;
    int d = tid & 15, sg = tid >> 4;
    float acc = 0.f;
    for (int k = sg * 320; k < sg * 320 + 320; k++) acc += cl[k] * w[k * DD + d];
    ps[sg][d] = acc;
    __syncthreads();
    if (tid < DD) {
        float o = ps[0][tid] + ps[1][tid] + ps[2][tid] + ps[3][tid] + pb[node1 * DD + tid];
        outs[(size_t)bid * DD + tid] = o;
    }
}

extern "C" void kernel_launch(void* const* d_in, const int* in_sizes, int n_in,
                              void* d_out, int out_size, void* d_ws, size_t ws_size,
                              hipStream_t stream) {
    const float* program_emb = (const float*)d_in[0];
    const float* h0       = (const float*)d_in[1];
    const float* node_emb = (const float*)d_in[2];
    const float* label_emb= (const float*)d_in[3];
    const float* w_ih     = (const float*)d_in[4];
    const float* w_hh     = (const float*)d_in[5];
    const float* b_ih     = (const float*)d_in[6];
    const float* b_hh     = (const float*)d_in[7];
    const float* ws1      = (const float*)d_in[8];
    const float* ws2      = (const float*)d_in[9];
    const float* pred_w   = (const float*)d_in[10];
    const float* pred_b   = (const float*)d_in[11];
    const int*   trace    = (const int*)d_in[12];
    const int*   na       = (const int*)d_in[13];

    float* ws = (float*)d_ws;
    float* store   = ws + 0;          // 64*127*256      = 2,080,768
    float* wihT    = ws + 2080768;    // 856*768         =   657,408
    float* ws1T    = ws + 2738176;    // 256*256         =    65,536
    float* prog_t  = ws + 2803712;    // 64*768          =    49,152
    float* node_t  = ws + 2852864;    // 2001*768        = 1,536,768
    float* sbuf    = ws + 4389632;    // 64*127*5        =    40,640
    float* ebuf    = ws + 4430272;    //                 =    40,640
    float* rD      = ws + 4470912;    //                 =    40,640
    float* label_p = ws + 4511568;    // 127*64*768      = 6,242,304   [dead after rec]
    float* Ubuf    = ws + 10753872;   // 8128*256        = 2,080,768   [dead after k_scores]
    _Float16* whh16 = (_Float16*)(ws + 12834640); // 768*256 f16 = 98,304 floats [dead after rec]
    float* ctx     = ws + 4511568;    // 127*64*1280     = 10,403,840  (aliases label_p/Ubuf/whh16; written in P3 only)

    float* outs = (float*)d_out;
    float* alph = outs + T1 * BB * DD;   // offset 130048

    // P1: static precompute
    k_transpose<<<2568, 256, 0, stream>>>(w_ih, wihT, G3, 856);
    k_transpose<<<256, 256, 0, stream>>>(ws1, ws1T, HID, HID);
    k_cvt<<<768, 256, 0, stream>>>(w_hh, whh16, G3 * HID);
    k_gemm<<<12,   256, 0, stream>>>(program_emb, wihT, prog_t, b_ih, nullptr, nullptr, 0, 64,   256, G3, 12, 300, 0);
    k_gemm<<<384,  256, 0, stream>>>(node_emb,    wihT, node_t, nullptr, nullptr, nullptr, 1, 2001, 300, G3, 12, 556, 0);
    k_gemm<<<1524, 256, 0, stream>>>(label_emb,   wihT, label_p, nullptr, trace, na,       2, 8128, 300, G3, 12, 0,   0);

    // P2: sequential recurrence — per-batch blocks, no grid barrier
    rec2_kernel<<<32, 512, 0, stream>>>(h0, whh16, b_hh, prog_t, node_t, label_p, trace, store);

    // P3: parallel attention + prediction
    k_gemm<<<508, 256, 0, stream>>>(store, ws1T, Ubuf, nullptr, nullptr, nullptr, 3, 8128, 256, HID, 4, 0, 1);
    k_scores<<<159, 256, 0, stream>>>(Ubuf, ws2, sbuf);
    k_softmax_scan<<<1, 512, 0, stream>>>(sbuf, ebuf, rD);
    k_alphas<<<20162, 256, 0, stream>>>(ebuf, rD, alph);
    k_ctx<<<320, 256, 0, stream>>>(ebuf, rD, store, ctx);
    k_pred<<<8128, 64, 0, stream>>>(ctx, pred_w, pred_b, trace, outs);
}

// Round 5
// 725.742 us; speedup vs baseline: 7.7506x; 1.2327x over previous
//
#include <hip/hip_runtime.h>
#include <hip/hip_bf16.h>
#include <math.h>

#define BB 64
#define TT 128
#define T1 127
#define NNODE 2000
#define EE 300
#define HID 256
#define NHEADS 5
#define DD 16
#define G3 768
#define ATT 1280

typedef _Float16 h2_t __attribute__((ext_vector_type(2)));

__device__ __forceinline__ float fdot2(h2_t a, h2_t b, float c) {
#if __has_builtin(__builtin_amdgcn_fdot2)
    return __builtin_amdgcn_fdot2(a, b, c, false);
#else
    return c + (float)a[0] * (float)b[0] + (float)a[1] * (float)b[1];
#endif
}

// ---------------- transpose (elementwise) ----------------
__global__ void k_transpose(const float* __restrict__ src, float* __restrict__ dst, int R, int C) {
    int idx = blockIdx.x * 256 + threadIdx.x;
    if (idx < R * C) {
        int r = idx / C, c = idx % C;
        dst[c * R + r] = src[idx];
    }
}

// ---------------- f32 -> f16 convert ----------------
__global__ void k_cvt(const float* __restrict__ src, _Float16* __restrict__ dst, int n) {
    int i = blockIdx.x * 256 + threadIdx.x;
    if (i < n) dst[i] = (_Float16)src[i];
}

// ---------------- tiled f32 GEMM with gather modes (R2-proven) ----------------
__global__ __launch_bounds__(256) void k_gemm(
    const float* __restrict__ A, const float* __restrict__ Bmat,
    float* __restrict__ out, const float* __restrict__ bias,
    const int* __restrict__ trace, const int* __restrict__ na,
    int mode, int M, int K, int N, int ntiles, int brow0, int dotanh)
{
    __shared__ float As[64][17];
    __shared__ float Bs[16][65];
    __shared__ int baseLds[64];
    __shared__ int validLds[64];
    int tid = threadIdx.x;
    int bm = blockIdx.x / ntiles, bn = blockIdx.x % ntiles;
    int m0 = bm * 64, n0 = bn * 64;
    if (tid < 64) {
        int m = m0 + tid;
        int valid = (m < M) ? 1 : 0;
        int base = 0;
        if (valid) {
            if (mode == 2) {
                int i = m >> 6, b = m & 63;
                int node = trace[b * TT + i];
                int asg = (node < NNODE) ? na[b * NNODE + node] : 0;
                base = (node * DD + asg) * EE;
            } else {
                base = m * K;
            }
        }
        baseLds[tid] = base;
        validLds[tid] = valid;
    }
    __syncthreads();
    int tr = tid >> 4, tc = tid & 15;
    float acc[4][4];
#pragma unroll
    for (int x = 0; x < 4; x++)
#pragma unroll
        for (int y = 0; y < 4; y++) acc[x][y] = 0.f;
    int iters = (K + 15) >> 4;
    for (int it = 0; it < iters; it++) {
        int kk = it * 16;
#pragma unroll
        for (int l = 0; l < 4; l++) {
            int ii = tid + l * 256;
            int r = ii >> 4, c = ii & 15;
            float v = 0.f;
            if (validLds[r] && (kk + c) < K) v = A[(size_t)baseLds[r] + kk + c];
            As[r][c] = v;
        }
#pragma unroll
        for (int l = 0; l < 4; l++) {
            int ii = tid + l * 256;
            int c = ii >> 6, g = ii & 63;
            float v = 0.f;
            if ((kk + c) < K) v = Bmat[(size_t)(brow0 + kk + c) * N + n0 + g];
            Bs[c][g] = v;
        }
        __syncthreads();
#pragma unroll
        for (int c = 0; c < 16; c++) {
            float a0 = As[tr * 4 + 0][c], a1 = As[tr * 4 + 1][c];
            float a2 = As[tr * 4 + 2][c], a3 = As[tr * 4 + 3][c];
            float b0 = Bs[c][tc * 4 + 0], b1 = Bs[c][tc * 4 + 1];
            float b2 = Bs[c][tc * 4 + 2], b3 = Bs[c][tc * 4 + 3];
            acc[0][0] += a0 * b0; acc[0][1] += a0 * b1; acc[0][2] += a0 * b2; acc[0][3] += a0 * b3;
            acc[1][0] += a1 * b0; acc[1][1] += a1 * b1; acc[1][2] += a1 * b2; acc[1][3] += a1 * b3;
            acc[2][0] += a2 * b0; acc[2][1] += a2 * b1; acc[2][2] += a2 * b2; acc[2][3] += a2 * b3;
            acc[3][0] += a3 * b0; acc[3][1] += a3 * b1; acc[3][2] += a3 * b2; acc[3][3] += a3 * b3;
        }
        __syncthreads();
    }
#pragma unroll
    for (int x = 0; x < 4; x++) {
        int row = m0 + tr * 4 + x;
        if (row < M) {
#pragma unroll
            for (int y = 0; y < 4; y++) {
                float v = acc[x][y];
                int col = n0 + tc * 4 + y;
                if (bias) v += bias[col];
                if (dotanh) v = tanhf(v);
                out[(size_t)row * N + col] = v;
            }
        }
    }
}

// ---------------- GRU recurrence: 1 batch/block, weights register-resident ----------------
__global__ __launch_bounds__(512, 2) void rec3_kernel(
    const float* __restrict__ h0, const _Float16* __restrict__ whh16, const float* __restrict__ bhh,
    const float* __restrict__ prog_t, const float* __restrict__ node_t, const float* __restrict__ label_p,
    const int* __restrict__ trace, float* __restrict__ store)
{
    __shared__ float hs32[HID];
    __shared__ _Float16 hs16[HID];
    const int tid = threadIdx.x;
    const int s = tid & 1;       // K-half
    const int k = tid >> 1;      // output row 0..255
    const int b = blockIdx.x;

    if (tid < HID) {
        float v = h0[(size_t)b * HID + tid];
        hs32[tid] = v;
        hs16[tid] = (_Float16)v;
    }

    union H8 { uint4 u; h2_t h[4]; };
    H8 wR[16], wZ[16], wN[16];
    {
        const uint4* wrp = (const uint4*)(whh16 + (size_t)k * HID + s * 128);
        const uint4* wzp = (const uint4*)(whh16 + (size_t)(HID + k) * HID + s * 128);
        const uint4* wnp = (const uint4*)(whh16 + (size_t)(2 * HID + k) * HID + s * 128);
#pragma unroll
        for (int cc = 0; cc < 16; cc++) { wR[cc].u = wrp[cc]; wZ[cc].u = wzp[cc]; wN[cc].u = wnp[cc]; }
    }
    const float bhr = bhh[k], bhz = bhh[HID + k], bhn = bhh[2 * HID + k];
    const float pr = prog_t[b * G3 + k], pz = prog_t[b * G3 + HID + k], pn = prog_t[b * G3 + 2 * HID + k];
    __syncthreads();

    for (int i = 0; i < T1; i++) {
        float gir = 0.f, giz = 0.f, gin = 0.f;
        if (s == 0) {
            const int node = trace[b * TT + i];
            const float* lp = label_p + ((size_t)i * BB + b) * G3;
            const float* nt = node_t + (size_t)node * G3;
            gir = lp[k] + nt[k] + pr;
            giz = lp[HID + k] + nt[HID + k] + pz;
            gin = lp[2 * HID + k] + nt[2 * HID + k] + pn;
        }
        const uint4* h8 = (const uint4*)(hs16 + s * 128);
        float ar = 0.f, az = 0.f, an = 0.f;
#pragma unroll
        for (int cc = 0; cc < 16; cc++) {
            H8 hv; hv.u = h8[cc];
#pragma unroll
            for (int j = 0; j < 4; j++) {
                ar = fdot2(wR[cc].h[j], hv.h[j], ar);
                az = fdot2(wZ[cc].h[j], hv.h[j], az);
                an = fdot2(wN[cc].h[j], hv.h[j], an);
            }
        }
        ar += __shfl_xor(ar, 1); az += __shfl_xor(az, 1); an += __shfl_xor(an, 1);
        __syncthreads();   // all reads of hs16 done
        if (s == 0) {
            float r = 1.f / (1.f + expf(-(gir + ar + bhr)));
            float z = 1.f / (1.f + expf(-(giz + az + bhz)));
            float n = tanhf(gin + r * (an + bhn));
            float hold = hs32[k];
            float hnew = (1.f - z) * n + z * hold;
            hs32[k] = hnew;
            hs16[k] = (_Float16)hnew;
            store[((size_t)b * T1 + i) * HID + k] = hnew;
        }
        __syncthreads();   // writes visible for next step
    }
}

// ---------------- scores = U @ ws2^T ----------------
__global__ void k_scores(const float* __restrict__ U, const float* __restrict__ ws2, float* __restrict__ sbuf) {
    int flat = blockIdx.x * 256 + threadIdx.x;
    if (flat < BB * T1 * NHEADS) {
        int m = flat / NHEADS, h = flat % NHEADS;
        const float* u = U + (size_t)m * HID;
        const float* w = ws2 + h * HID;
        float acc = 0.f;
        for (int c = 0; c < HID; c += 4) {
            float4 u4 = *(const float4*)(u + c);
            float4 w4 = *(const float4*)(w + c);
            acc += u4.x * w4.x + u4.y * w4.y + u4.z * w4.z + u4.w * w4.w;
        }
        sbuf[flat] = acc;
    }
}

// ---------------- per-(b,h) global max + exp + prefix denominators ----------------
__global__ void k_softmax_scan(const float* __restrict__ sbuf, float* __restrict__ ebuf, float* __restrict__ rD) {
    int tid = threadIdx.x;
    if (tid < BB * NHEADS) {
        int b = tid / NHEADS, h = tid % NHEADS;
        const float* s = sbuf + (size_t)b * T1 * NHEADS + h;
        float m = -1e30f;
        for (int t = 0; t < T1; t++) m = fmaxf(m, s[t * NHEADS]);
        float d = 0.f;
        for (int t = 0; t < T1; t++) {
            float e = expf(s[t * NHEADS] - m);
            ebuf[(b * T1 + t) * NHEADS + h] = e;
            d += e;
            rD[(b * T1 + t) * NHEADS + h] = 1.f / d;
        }
    }
}

// ---------------- alphas output ----------------
__global__ void k_alphas(const float* __restrict__ ebuf, const float* __restrict__ rD, float* __restrict__ alph) {
    int flat = blockIdx.x * 256 + threadIdx.x;
    const int TOT = T1 * BB * T1 * NHEADS;
    if (flat < TOT) {
        int i = flat / (BB * T1 * NHEADS);
        int rem = flat % (BB * T1 * NHEADS);
        int b = rem / (T1 * NHEADS);
        int rem2 = rem % (T1 * NHEADS);
        int t = rem2 / NHEADS, h = rem2 % NHEADS;
        float v = 0.f;
        if (t <= i) v = ebuf[(b * T1 + t) * NHEADS + h] * rD[(b * T1 + i) * NHEADS + h];
        alph[flat] = v;
    }
}

// ---------------- ctx prefix scan ----------------
__global__ void k_ctx(const float* __restrict__ ebuf, const float* __restrict__ rD,
                      const float* __restrict__ store, float* __restrict__ ctx) {
    int b = blockIdx.x / NHEADS, h = blockIdx.x % NHEADS;
    int k = threadIdx.x;
    float acc = 0.f;
    for (int t = 0; t < T1; t++) {
        float e = ebuf[(b * T1 + t) * NHEADS + h];
        float r = rD[(b * T1 + t) * NHEADS + h];
        acc += e * store[((size_t)b * T1 + t) * HID + k];
        ctx[((size_t)t * BB + b) * ATT + h * HID + k] = acc * r;
    }
}

// ---------------- routed prediction heads (R2-proven) ----------------
__global__ __launch_bounds__(64) void k_pred(const float* __restrict__ ctx, const float* __restrict__ pw,
                                             const float* __restrict__ pb, const int* __restrict__ trace,
                                             float* __restrict__ outs) {
    __shared__ float cl[ATT];
    __shared__ float ps[4][DD];
    int bid = blockIdx.x;           // i*64 + b
    int i = bid >> 6, b = bid & 63;
    int tid = threadIdx.x;
    for (int idx = tid; idx < ATT; idx += 64) cl[idx] = ctx[(size_t)bid * ATT + idx];
    __syncthreads();
    int node1 = trace[b * TT + i + 1];
    const float* w = pw + (size_t)node1 * ATT * DD;
    int d = tid & 15, sg = tid >> 4;
    float acc = 0.f;
    for (int k = sg * 320; k < sg * 320 + 320; k++) acc += cl[k] * w[k * DD + d];
    ps[sg][d] = acc;
    __syncthreads();
    if (tid < DD) {
        float o = ps[0][tid] + ps[1][tid] + ps[2][tid] + ps[3][tid] + pb[node1 * DD + tid];
        outs[(size_t)bid * DD + tid] = o;
    }
}

extern "C" void kernel_launch(void* const* d_in, const int* in_sizes, int n_in,
                              void* d_out, int out_size, void* d_ws, size_t ws_size,
                              hipStream_t stream) {
    const float* program_emb = (const float*)d_in[0];
    const float* h0       = (const float*)d_in[1];
    const float* node_emb = (const float*)d_in[2];
    const float* label_emb= (const float*)d_in[3];
    const float* w_ih     = (const float*)d_in[4];
    const float* w_hh     = (const float*)d_in[5];
    const float* b_ih     = (const float*)d_in[6];
    const float* b_hh     = (const float*)d_in[7];
    const float* ws1      = (const float*)d_in[8];
    const float* ws2      = (const float*)d_in[9];
    const float* pred_w   = (const float*)d_in[10];
    const float* pred_b   = (const float*)d_in[11];
    const int*   trace    = (const int*)d_in[12];
    const int*   na       = (const int*)d_in[13];

    // ---- R2-exact workspace layout ----
    float* ws = (float*)d_ws;
    float* store   = ws + 0;          // 64*127*256      = 2,080,768
    float* wihT    = ws + 2080768;    // 856*768         =   657,408
    float* ws1T    = ws + 2738176;    // 256*256         =    65,536
    float* prog_t  = ws + 2803712;    // 64*768          =    49,152
    float* node_t  = ws + 2852864;    // 2001*768        = 1,536,768
    float* sbuf    = ws + 4389632;    // 64*127*5        =    40,640
    float* ebuf    = ws + 4430272;    //                 =    40,640
    float* rD      = ws + 4470912;    //                 =    40,640
    float* label_p = ws + 4511568;    // 127*64*768      = 6,242,304   [dead after rec]
    float* Ubuf    = ws + 10753872;   // 8128*256        = 2,080,768   [dead after k_scores]
    _Float16* whh16 = (_Float16*)(ws + 12834640); // 768*256 f16 = 49,152 floats [dead after rec]
    float* ctx     = ws + 4511568;    // 127*64*1280     = 10,403,840  (aliases label_p/Ubuf/whh16; written in P3 only)

    float* outs = (float*)d_out;
    float* alph = outs + T1 * BB * DD;   // offset 130048

    // P1: static precompute
    k_transpose<<<2568, 256, 0, stream>>>(w_ih, wihT, G3, 856);
    k_transpose<<<256, 256, 0, stream>>>(ws1, ws1T, HID, HID);
    k_cvt<<<768, 256, 0, stream>>>(w_hh, whh16, G3 * HID);
    k_gemm<<<12,   256, 0, stream>>>(program_emb, wihT, prog_t, b_ih, nullptr, nullptr, 0, 64,   256, G3, 12, 300, 0);
    k_gemm<<<384,  256, 0, stream>>>(node_emb,    wihT, node_t, nullptr, nullptr, nullptr, 1, 2001, 300, G3, 12, 556, 0);
    k_gemm<<<1524, 256, 0, stream>>>(label_emb,   wihT, label_p, nullptr, trace, na,       2, 8128, 300, G3, 12, 0,   0);

    // P2: sequential recurrence — ONLY change vs R2: rec3 (register-resident weights)
    rec3_kernel<<<64, 512, 0, stream>>>(h0, whh16, b_hh, prog_t, node_t, label_p, trace, store);

    // P3: parallel attention + prediction (R2-exact)
    k_gemm<<<508, 256, 0, stream>>>(store, ws1T, Ubuf, nullptr, nullptr, nullptr, 3, 8128, 256, HID, 4, 0, 1);
    k_scores<<<159, 256, 0, stream>>>(Ubuf, ws2, sbuf);
    k_softmax_scan<<<1, 512, 0, stream>>>(sbuf, ebuf, rD);
    k_alphas<<<20162, 256, 0, stream>>>(ebuf, rD, alph);
    k_ctx<<<320, 256, 0, stream>>>(ebuf, rD, store, ctx);
    k_pred<<<8128, 64, 0, stream>>>(ctx, pred_w, pred_b, trace, outs);
}

// Round 6
// 527.789 us; speedup vs baseline: 10.6575x; 1.3751x over previous
//
#include <hip/hip_runtime.h>
#include <hip/hip_bf16.h>
#include <math.h>

#define BB 64
#define TT 128
#define T1 127
#define NNODE 2000
#define EE 300
#define HID 256
#define NHEADS 5
#define DD 16
#define G3 768
#define ATT 1280

typedef _Float16 h2_t __attribute__((ext_vector_type(2)));
typedef short short8 __attribute__((ext_vector_type(8)));
typedef float f32x4 __attribute__((ext_vector_type(4)));

__device__ __forceinline__ float dot2(h2_t a, h2_t b, float c) {
    asm("v_dot2_f32_f16 %0, %1, %2, %0" : "+v"(c) : "v"(a), "v"(b));
    return c;
}

__device__ __forceinline__ unsigned short f2bf(float f) {
    unsigned u = __float_as_uint(f);
    unsigned r = (u + 0x7FFFu + ((u >> 16) & 1u)) >> 16;   // RNE
    return (unsigned short)r;
}

// ---------------- transpose + f32->bf16 ----------------
__global__ void k_tcvt(const float* __restrict__ src, unsigned short* __restrict__ dst, int R, int C) {
    int idx = blockIdx.x * 256 + threadIdx.x;
    if (idx < R * C) {
        int r = idx / C, c = idx % C;
        dst[c * R + r] = f2bf(src[idx]);
    }
}

// ---------------- f32 -> f16 convert ----------------
__global__ void k_cvt(const float* __restrict__ src, _Float16* __restrict__ dst, int n) {
    int i = blockIdx.x * 256 + threadIdx.x;
    if (i < n) dst[i] = (_Float16)src[i];
}

// ---------------- bf16 MFMA GEMM (pun-free staging) ----------------
// out[M][N](f32) = A[M][K](f32, gathered, cvt->bf16) x B16[brow0+k][N](bf16)
// mode 0: A row base = m*strideA      mode 2: label gather via trace/na
__global__ __launch_bounds__(256) void k_mgemm(
    const float* __restrict__ A, const unsigned short* __restrict__ B16,
    float* __restrict__ out, const float* __restrict__ bias,
    const int* __restrict__ trace, const int* __restrict__ na,
    int mode, int M, int K, int N, int strideA, int ntiles, int brow0, int Bld, int dotanh)
{
    __shared__ short As[64][40];   // 64 rows x 32 k (pitch 40 shorts = 80 B, 16B-aligned frags)
    __shared__ short Bt[64][40];   // 64 cols x 32 k
    __shared__ int baseLds[64];
    __shared__ int validLds[64];
    int tid = threadIdx.x;
    int bm = blockIdx.x / ntiles, bn = blockIdx.x % ntiles;
    int m0 = bm * 64, n0 = bn * 64;
    if (tid < 64) {
        int m = m0 + tid;
        int valid = (m < M) ? 1 : 0;
        int base = 0;
        if (valid) {
            if (mode == 2) {
                int i = m >> 6, bb = m & 63;
                int node = trace[bb * TT + i];
                int asg = (node < NNODE) ? na[bb * NNODE + node] : 0;
                base = (node * DD + asg) * EE;
            } else {
                base = m * strideA;
            }
        }
        baseLds[tid] = base;
        validLds[tid] = valid;
    }
    __syncthreads();

    int wv = tid >> 6, l = tid & 63;
    int lr = l & 15, lg = l >> 4;
    f32x4 acc[4];
#pragma unroll
    for (int cb = 0; cb < 4; cb++) acc[cb] = (f32x4){0.f, 0.f, 0.f, 0.f};

    int ar = tid >> 2, aq = tid & 3;   // A staging: row, k-quarter (8 k each)
    int bk = tid >> 3, bq = tid & 7;   // B staging: k, n-octet (8 n each)
    int nsteps = (K + 31) >> 5;
    for (int it = 0; it < nsteps; it++) {
        int kk = it * 32;
        {   // stage A (f32 -> bf16)
            int base = baseLds[ar], val = validLds[ar];
            short8 t1;
#pragma unroll
            for (int j = 0; j < 8; j++) {
                int kx = kk + aq * 8 + j;
                float v = (val && kx < K) ? A[(size_t)base + kx] : 0.f;
                t1[j] = (short)f2bf(v);
            }
            *(short8*)&As[ar][aq * 8] = t1;
        }
        {   // stage B (bf16), transpose into Bt[n][k]
            int kx = kk + bk;
            short8 t2;
            if (kx < K) {
                t2 = *(const short8*)(B16 + (size_t)(brow0 + kx) * Bld + n0 + bq * 8);
            } else {
#pragma unroll
                for (int j = 0; j < 8; j++) t2[j] = 0;
            }
#pragma unroll
            for (int j = 0; j < 8; j++) Bt[bq * 8 + j][bk] = t2[j];
        }
        __syncthreads();
        short8 a = *(const short8*)&As[wv * 16 + lr][lg * 8];
#pragma unroll
        for (int cb = 0; cb < 4; cb++) {
            short8 bfr = *(const short8*)&Bt[cb * 16 + lr][lg * 8];
            acc[cb] = __builtin_amdgcn_mfma_f32_16x16x32_bf16(a, bfr, acc[cb], 0, 0, 0);
        }
        __syncthreads();
    }
#pragma unroll
    for (int cb = 0; cb < 4; cb++) {
        int col = n0 + cb * 16 + lr;
#pragma unroll
        for (int q = 0; q < 4; q++) {
            int row = m0 + wv * 16 + lg * 4 + q;
            if (row < M) {
                float v = acc[cb][q];
                if (bias) v += bias[col];
                if (dotanh) v = tanhf(v);
                out[(size_t)row * N + col] = v;
            }
        }
    }
}

// ---------------- gsum = label_p + node_t[trace] + prog_t (in-place into label_p) ----------------
__global__ void k_addgi(float* __restrict__ lp, const float* __restrict__ node_t,
                        const float* __restrict__ prog_t, const int* __restrict__ trace) {
    int idx = blockIdx.x * 256 + threadIdx.x;   // over T1*BB*(G3/4)
    const int NG4 = G3 / 4;
    if (idx < T1 * BB * NG4) {
        int g4 = idx % NG4;
        int rest = idx / NG4;
        int b = rest % BB;
        int i = rest / BB;
        int node = trace[b * TT + i];
        float4 v = *(float4*)(lp + (size_t)idx * 4);
        float4 nt = *(const float4*)(node_t + (size_t)node * G3 + g4 * 4);
        float4 pt = *(const float4*)(prog_t + (size_t)b * G3 + g4 * 4);
        v.x += nt.x + pt.x; v.y += nt.y + pt.y; v.z += nt.z + pt.z; v.w += nt.w + pt.w;
        *(float4*)(lp + (size_t)idx * 4) = v;
    }
}

// ---------------- GRU recurrence: 1 batch/block, asm dot2, gi prefetch ----------------
__global__ __launch_bounds__(512, 2) void rec4_kernel(
    const float* __restrict__ h0, const _Float16* __restrict__ whh16, const float* __restrict__ bhh,
    const float* __restrict__ gsum, float* __restrict__ store)
{
    __shared__ float hs32[HID];
    __shared__ _Float16 hs16[HID];
    const int tid = threadIdx.x;
    const int s = tid & 1;       // K-half
    const int k = tid >> 1;      // output row 0..255
    const int b = blockIdx.x;

    if (tid < HID) {
        float v = h0[(size_t)b * HID + tid];
        hs32[tid] = v;
        hs16[tid] = (_Float16)v;
    }

    union H8 { uint4 u; h2_t h[4]; };
    H8 wR[16], wZ[16], wN[16];
    {
        const uint4* wrp = (const uint4*)(whh16 + (size_t)k * HID + s * 128);
        const uint4* wzp = (const uint4*)(whh16 + (size_t)(HID + k) * HID + s * 128);
        const uint4* wnp = (const uint4*)(whh16 + (size_t)(2 * HID + k) * HID + s * 128);
#pragma unroll
        for (int cc = 0; cc < 16; cc++) { wR[cc].u = wrp[cc]; wZ[cc].u = wzp[cc]; wN[cc].u = wnp[cc]; }
    }
    const float bhr = bhh[k], bhz = bhh[HID + k], bhn = bhh[2 * HID + k];
    __syncthreads();

    float gr_c = 0.f, gz_c = 0.f, gn_c = 0.f;
    if (s == 0) {
        const float* lp = gsum + (size_t)b * G3;   // i=0
        gr_c = lp[k]; gz_c = lp[HID + k]; gn_c = lp[2 * HID + k];
    }

    for (int i = 0; i < T1; i++) {
        float gr_n = 0.f, gz_n = 0.f, gn_n = 0.f;
        if (s == 0 && i + 1 < T1) {
            const float* lp = gsum + ((size_t)(i + 1) * BB + b) * G3;
            gr_n = lp[k]; gz_n = lp[HID + k]; gn_n = lp[2 * HID + k];
        }
        const uint4* h8 = (const uint4*)(hs16 + s * 128);
        float ar = 0.f, az = 0.f, an = 0.f;
#pragma unroll
        for (int cc = 0; cc < 16; cc++) {
            H8 hv; hv.u = h8[cc];
#pragma unroll
            for (int j = 0; j < 4; j++) {
                ar = dot2(wR[cc].h[j], hv.h[j], ar);
                az = dot2(wZ[cc].h[j], hv.h[j], az);
                an = dot2(wN[cc].h[j], hv.h[j], an);
            }
        }
        ar += __shfl_xor(ar, 1); az += __shfl_xor(az, 1); an += __shfl_xor(an, 1);
        __syncthreads();   // all reads of hs16 done
        if (s == 0) {
            float r = 1.f / (1.f + expf(-(gr_c + ar + bhr)));
            float z = 1.f / (1.f + expf(-(gz_c + az + bhz)));
            float n = tanhf(gn_c + r * (an + bhn));
            float hold = hs32[k];
            float hnew = (1.f - z) * n + z * hold;
            hs32[k] = hnew;
            hs16[k] = (_Float16)hnew;
            store[((size_t)b * T1 + i) * HID + k] = hnew;
        }
        __syncthreads();   // writes visible for next step
        gr_c = gr_n; gz_c = gz_n; gn_c = gn_n;
    }
}

// ---------------- scores = U @ ws2^T ----------------
__global__ void k_scores(const float* __restrict__ U, const float* __restrict__ ws2, float* __restrict__ sbuf) {
    int flat = blockIdx.x * 256 + threadIdx.x;
    if (flat < BB * T1 * NHEADS) {
        int m = flat / NHEADS, h = flat % NHEADS;
        const float* u = U + (size_t)m * HID;
        const float* w = ws2 + h * HID;
        float acc = 0.f;
        for (int c = 0; c < HID; c += 4) {
            float4 u4 = *(const float4*)(u + c);
            float4 w4 = *(const float4*)(w + c);
            acc += u4.x * w4.x + u4.y * w4.y + u4.z * w4.z + u4.w * w4.w;
        }
        sbuf[flat] = acc;
    }
}

// ---------------- per-(b,h) global max + exp + prefix denominators ----------------
__global__ void k_softmax_scan(const float* __restrict__ sbuf, float* __restrict__ ebuf, float* __restrict__ rD) {
    int tid = threadIdx.x;
    if (tid < BB * NHEADS) {
        int b = tid / NHEADS, h = tid % NHEADS;
        const float* s = sbuf + (size_t)b * T1 * NHEADS + h;
        float m = -1e30f;
        for (int t = 0; t < T1; t++) m = fmaxf(m, s[t * NHEADS]);
        float d = 0.f;
        for (int t = 0; t < T1; t++) {
            float e = expf(s[t * NHEADS] - m);
            ebuf[(b * T1 + t) * NHEADS + h] = e;
            d += e;
            rD[(b * T1 + t) * NHEADS + h] = 1.f / d;
        }
    }
}

// ---------------- alphas output ----------------
__global__ void k_alphas(const float* __restrict__ ebuf, const float* __restrict__ rD, float* __restrict__ alph) {
    int flat = blockIdx.x * 256 + threadIdx.x;
    const int TOT = T1 * BB * T1 * NHEADS;
    if (flat < TOT) {
        int i = flat / (BB * T1 * NHEADS);
        int rem = flat % (BB * T1 * NHEADS);
        int b = rem / (T1 * NHEADS);
        int rem2 = rem % (T1 * NHEADS);
        int t = rem2 / NHEADS, h = rem2 % NHEADS;
        float v = 0.f;
        if (t <= i) v = ebuf[(b * T1 + t) * NHEADS + h] * rD[(b * T1 + i) * NHEADS + h];
        alph[flat] = v;
    }
}

// ---------------- ctx prefix scan (LDS-staged e/rD, unrolled) ----------------
__global__ __launch_bounds__(256) void k_ctx(const float* __restrict__ ebuf, const float* __restrict__ rD,
                                             const float* __restrict__ store, float* __restrict__ ctx) {
    __shared__ float eL[T1], rL[T1];
    int b = blockIdx.x / NHEADS, h = blockIdx.x % NHEADS;
    int k = threadIdx.x;
    if (k < T1) {
        eL[k] = ebuf[(b * T1 + k) * NHEADS + h];
        rL[k] = rD[(b * T1 + k) * NHEADS + h];
    }
    __syncthreads();
    float acc = 0.f;
#pragma unroll 4
    for (int t = 0; t < T1; t++) {
        acc += eL[t] * store[((size_t)b * T1 + t) * HID + k];
        ctx[((size_t)t * BB + b) * ATT + h * HID + k] = acc * rL[t];
    }
}

// ---------------- routed prediction heads (R2/R5-proven) ----------------
__global__ __launch_bounds__(64) void k_pred(const float* __restrict__ ctx, const float* __restrict__ pw,
                                             const float* __restrict__ pb, const int* __restrict__ trace,
                                             float* __restrict__ outs) {
    __shared__ float cl[ATT];
    __shared__ float ps[4][DD];
    int bid = blockIdx.x;           // i*64 + b
    int i = bid >> 6, b = bid & 63;
    int tid = threadIdx.x;
    for (int idx = tid; idx < ATT; idx += 64) cl[idx] = ctx[(size_t)bid * ATT + idx];
    __syncthreads();
    int node1 = trace[b * TT + i + 1];
    const float* w = pw + (size_t)node1 * ATT * DD;
    int d = tid & 15, sg = tid >> 4;
    float acc = 0.f;
    for (int k = sg * 320; k < sg * 320 + 320; k++) acc += cl[k] * w[k * DD + d];
    ps[sg][d] = acc;
    __syncthreads();
    if (tid < DD) {
        float o = ps[0][tid] + ps[1][tid] + ps[2][tid] + ps[3][tid] + pb[node1 * DD + tid];
        outs[(size_t)bid * DD + tid] = o;
    }
}

extern "C" void kernel_launch(void* const* d_in, const int* in_sizes, int n_in,
                              void* d_out, int out_size, void* d_ws, size_t ws_size,
                              hipStream_t stream) {
    const float* program_emb = (const float*)d_in[0];
    const float* h0       = (const float*)d_in[1];
    const float* node_emb = (const float*)d_in[2];
    const float* label_emb= (const float*)d_in[3];
    const float* w_ih     = (const float*)d_in[4];
    const float* w_hh     = (const float*)d_in[5];
    const float* b_ih     = (const float*)d_in[6];
    const float* b_hh     = (const float*)d_in[7];
    const float* ws1      = (const float*)d_in[8];
    const float* ws2      = (const float*)d_in[9];
    const float* pred_w   = (const float*)d_in[10];
    const float* pred_b   = (const float*)d_in[11];
    const int*   trace    = (const int*)d_in[12];
    const int*   na       = (const int*)d_in[13];

    // ---- R5-compatible layout (floats). ctx span [4,511,568 .. 14,915,408) proven in R2/R5. ----
    float*          ws      = (float*)d_ws;
    float*          store   = ws + 0;           // [0 .. 2,080,768)
    unsigned short* wihT16  = (unsigned short*)(ws + 2080768);   // 657,408 bf16 -> ends fl 2,409,472
    unsigned short* ws1T16  = (unsigned short*)(ws + 2409472);   //  65,536 bf16 -> ends fl 2,442,240
    float*          prog_t  = ws + 2803712;     // [.. 2,852,864)
    float*          node_t  = ws + 2852864;     // [.. 4,389,632)
    float*          sbuf    = ws + 4389632;     // 40,640
    float*          ebuf    = ws + 4430272;     // 40,640
    float*          rD      = ws + 4470912;     // 40,640
    float*          label_p = ws + 4511568;     // [.. 10,753,872)  (gsum in-place; dead after rec4)
    float*          Ubuf    = ws + 10753872;    // [.. 12,834,640)  (dead after k_scores)
    _Float16*       whh16   = (_Float16*)(ws + 12834640);        // 49,152 fl (dead after rec4)
    float*          ctx     = ws + 4511568;     // [.. 14,915,408)  (aliases label_p/Ubuf/whh16)

    float* outs = (float*)d_out;
    float* alph = outs + T1 * BB * DD;   // offset 130048

    // P1: static precompute (bf16 MFMA GEMMs)
    k_tcvt<<<2568, 256, 0, stream>>>(w_ih, wihT16, G3, 856);
    k_tcvt<<<256, 256, 0, stream>>>(ws1, ws1T16, HID, HID);
    k_cvt<<<768, 256, 0, stream>>>(w_hh, whh16, G3 * HID);
    //                      A            B       out      bias    trace    na     mode  M     K    N    sA   nt  br0  Bld  tanh
    k_mgemm<<<12,   256, 0, stream>>>(program_emb, wihT16, prog_t, b_ih,   nullptr, nullptr, 0, 64,   256, G3,  256, 12, 300, G3, 0);
    k_mgemm<<<384,  256, 0, stream>>>(node_emb,    wihT16, node_t, nullptr, nullptr, nullptr, 0, 2001, 300, G3,  300, 12, 556, G3, 0);
    k_mgemm<<<1524, 256, 0, stream>>>(label_emb,   wihT16, label_p, nullptr, trace,  na,      2, 8128, 300, G3,  300, 12, 0,   G3, 0);
    k_addgi<<<6096, 256, 0, stream>>>(label_p, node_t, prog_t, trace);

    // P2: sequential recurrence
    rec4_kernel<<<64, 512, 0, stream>>>(h0, whh16, b_hh, label_p, store);

    // P3: parallel attention + prediction
    k_mgemm<<<508, 256, 0, stream>>>(store, ws1T16, Ubuf, nullptr, nullptr, nullptr, 0, 8128, 256, HID, 256, 4, 0, HID, 1);
    k_scores<<<159, 256, 0, stream>>>(Ubuf, ws2, sbuf);
    k_softmax_scan<<<1, 512, 0, stream>>>(sbuf, ebuf, rD);
    k_alphas<<<20162, 256, 0, stream>>>(ebuf, rD, alph);
    k_ctx<<<320, 256, 0, stream>>>(ebuf, rD, store, ctx);
    k_pred<<<8128, 64, 0, stream>>>(ctx, pred_w, pred_b, trace, outs);
}